// Round 6
// baseline (181.835 us; speedup 1.0000x reference)
//
#include <hip/hip_runtime.h>
#include <hip/hip_bf16.h>

#define NB 16
#define NN 512
#define NH 8
#define NF 128
#define NEG_SLOPE 0.2f

typedef short bf16x8 __attribute__((ext_vector_type(8)));
typedef unsigned short u16x8 __attribute__((ext_vector_type(8)));
typedef float f32x4 __attribute__((ext_vector_type(4)));

__device__ inline unsigned short f2bf(float x) {
    __hip_bfloat16 b = __float2bfloat16(x);          // RNE hardware convert
    return __builtin_bit_cast(unsigned short, b);
}
__device__ inline float bf2f(unsigned short u) {
    return __uint_as_float(((unsigned int)u) << 16);
}

// ---------------- fused prep: mb, h hi/lo split, W^T hi/lo split, wa vectors ----------------
__global__ __launch_bounds__(256) void prep_all_kernel(
    const float* __restrict__ h, const int* __restrict__ adj,
    const float* __restrict__ bias, const float* __restrict__ W,
    const float* __restrict__ a,
    float* __restrict__ mb,
    unsigned short* __restrict__ hHi, unsigned short* __restrict__ hLo,
    unsigned short* __restrict__ wtHi, unsigned short* __restrict__ wtLo,
    float* __restrict__ wasrc, float* __restrict__ wadst)
{
    int t = blockIdx.x * 256 + threadIdx.x;      // grid covers NB*NN*NF = 1048576
    {
        float v = h[t];
        unsigned short hi = f2bf(v);
        hHi[t] = hi;
        hLo[t] = f2bf(v - bf2f(hi));
    }
    if (t < NN * NN) mb[t] = (adj[t] != 0) ? bias[t] : -1.0e30f;
    if (t < NH * NF * NF) {
        // coalesced READ of W in natural order; scattered 2B writes (fire-and-forget)
        float v = W[t];                          // t = (hh*128 + k)*128 + f
        int hh = t >> 14;
        int k  = (t >> 7) & 127;
        int f  = t & 127;
        int u  = (hh * NF + f) * NF + k;         // wt[f_global][k]
        unsigned short hi = f2bf(v);
        wtHi[u] = hi;
        wtLo[u] = f2bf(v - bf2f(hi));
    }
    if (t < NH * NF) {
        int hh = t >> 7, i = t & 127;
        const float* wrow = W + (hh * NF + i) * NF;
        const float* asr = a + hh * 2 * NF;
        const float* ads = asr + NF;
        float s1 = 0.f, s2 = 0.f;
        #pragma unroll 4
        for (int f = 0; f < NF; ++f) {
            float w = wrow[f];
            s1 = fmaf(w, asr[f], s1);
            s2 = fmaf(w, ads[f], s2);
        }
        wasrc[t] = s1; wadst[t] = s2;
    }
}

// ---------------- scores: f32-exact; sdst stored transposed [b][h][n] ----------------
__global__ __launch_bounds__(256) void score_kernel(
    const float* __restrict__ h, const float* __restrict__ wasrc,
    const float* __restrict__ wadst, float* __restrict__ ssrc, float* __restrict__ sdstT)
{
    __shared__ float wsm[2][NH * (NF + 4)];
    int tid = threadIdx.x;
    for (int u = tid; u < NH * NF; u += 256) {
        int hh = u >> 7, f = u & 127;
        wsm[0][hh * (NF + 4) + f] = wasrc[u];
        wsm[1][hh * (NF + 4) + f] = wadst[u];
    }
    __syncthreads();
    int t = blockIdx.x * 256 + tid;           // over B*N*H
    int hh = t & 7;
    int bn = t >> 3;
    int b = bn >> 9, n = bn & 511;
    const float4* hrow = (const float4*)(h + (size_t)bn * NF);
    const float4* w1 = (const float4*)(&wsm[0][hh * (NF + 4)]);
    const float4* w2 = (const float4*)(&wsm[1][hh * (NF + 4)]);
    float s1 = 0.f, s2 = 0.f;
    #pragma unroll
    for (int u = 0; u < NF / 4; ++u) {
        float4 hv = hrow[u], a1 = w1[u], a2 = w2[u];
        s1 += hv.x * a1.x + hv.y * a1.y + hv.z * a1.z + hv.w * a1.w;
        s2 += hv.x * a2.x + hv.y * a2.y + hv.z * a2.z + hv.w * a2.w;
    }
    ssrc[t] = s1;
    sdstT[((size_t)(b * NH + hh)) * NN + n] = s2;
}

// ---------------- h_prime v2: wt-in-registers, streamed n-tiles -> hpT[b][hf][n] ----------------
// block = 4 waves (4 f-tiles of one (h,fgroup)), shared n-chunk of 128 rows.
// wave: preload 8 wt frags once; loop 8 n-tiles: {8 A loads, 12 MFMA, 1 ushort4 store}.
// XCD-clustered: same n-chunk => same (bx % 8).
__global__ __launch_bounds__(256, 4) void hprime_kernel(
    const unsigned short* __restrict__ hHi, const unsigned short* __restrict__ hLo,
    const unsigned short* __restrict__ wtHi, const unsigned short* __restrict__ wtLo,
    unsigned short* __restrict__ hpT)
{
    int bx = blockIdx.x;
    int nchunk = bx & 63;                      // 64 chunks of 128 n-rows
    int hfg = bx >> 6;                         // 0..15
    int hh = hfg >> 1, fg = hfg & 1;
    int tid = threadIdx.x;
    int wave = tid >> 6, lane = tid & 63;
    int col = lane & 15, kg = lane >> 4;
    int fbase = hh * NF + fg * 64 + wave * 16; // f_global tile base
    int n0g = nchunk * 128;
    int b = n0g >> 9;
    int nin = n0g & 511;

    // preload B (wt) fragments once: 4 k-steps x {hi,lo}
    const unsigned short* Bh = wtHi + (size_t)(fbase + col) * NF + kg * 8;
    const unsigned short* Bl = wtLo + (size_t)(fbase + col) * NF + kg * 8;
    bf16x8 bh[4], bl[4];
    #pragma unroll
    for (int ks = 0; ks < 4; ++ks) {
        bh[ks] = *(const bf16x8*)(Bh + ks * 32);
        bl[ks] = *(const bf16x8*)(Bl + ks * 32);
    }

    size_t outRow = ((size_t)b * (NH * NF) + fbase + col) * NN;   // f fixed per lane

    #pragma unroll 2
    for (int nt = 0; nt < 8; ++nt) {
        const unsigned short* Ah = hHi + (size_t)(n0g + nt * 16 + col) * NF + kg * 8;
        const unsigned short* Al = hLo + (size_t)(n0g + nt * 16 + col) * NF + kg * 8;
        bf16x8 ah[4], al[4];
        #pragma unroll
        for (int ks = 0; ks < 4; ++ks) {
            ah[ks] = *(const bf16x8*)(Ah + ks * 32);
            al[ks] = *(const bf16x8*)(Al + ks * 32);
        }
        f32x4 acc = {0.f, 0.f, 0.f, 0.f};
        #pragma unroll
        for (int ks = 0; ks < 4; ++ks) {
            acc = __builtin_amdgcn_mfma_f32_16x16x32_bf16(ah[ks], bh[ks], acc, 0, 0, 0);
            acc = __builtin_amdgcn_mfma_f32_16x16x32_bf16(al[ks], bh[ks], acc, 0, 0, 0);
            acc = __builtin_amdgcn_mfma_f32_16x16x32_bf16(ah[ks], bl[ks], acc, 0, 0, 0);
        }
        ushort4 u;
        u.x = f2bf(acc[0]); u.y = f2bf(acc[1]);
        u.z = f2bf(acc[2]); u.w = f2bf(acc[3]);
        *(ushort4*)&hpT[outRow + nin + nt * 16 + kg * 4] = u;
    }
}

// ---------------- attention v3: barrier-free register-flash PV, LDS head-mean ----------------
// grid 512: bx = b + 16*(ipair*2 + fhalf)  (same-b blocks share XCD class).
// 512 threads = 8 waves = 8 heads. Wave owns C[32 i][64 f] for its head; the MFMA
// A-fragment e(i=col, j=kg*8+v) is computed in-lane -> P never materializes.
// One barrier total (head-mean reduce in LDS), plain float4 stores.
__global__ __launch_bounds__(512, 4) void attn_kernel(
    const unsigned short* __restrict__ hpT, const float* __restrict__ mb,
    const float* __restrict__ ssrc, const float* __restrict__ sdstT,
    float* __restrict__ out)
{
    __shared__ float red[NH][32][64];          // 64 KB
    int bx = blockIdx.x;
    int b = bx & 15;
    int rest = bx >> 4;                        // 0..31
    int ipair = rest >> 1;                     // 0..15
    int fhalf = rest & 1;
    int i0 = ipair * 32;
    int f0 = fhalf * 64;
    int tid = threadIdx.x;
    int lane = tid & 63, h = tid >> 6;
    int col = lane & 15, kg = lane >> 4;

    const short one_bf = (short)0x3f80;
    const bf16x8 vone = {one_bf, one_bf, one_bf, one_bf, one_bf, one_bf, one_bf, one_bf};

    const float* sd = sdstT + (size_t)(b * NH + h) * NN;
    float s0 = ssrc[((size_t)(b * NN) + i0 + col) * NH + h];
    float s1 = ssrc[((size_t)(b * NN) + i0 + 16 + col) * NH + h];
    const float* mb0 = mb + (size_t)(i0 + col) * NN;
    const float* mb1 = mb + (size_t)(i0 + 16 + col) * NN;
    const unsigned short* Bbase = hpT + ((size_t)(b * NH + h) * NF + f0 + col) * NN;

    f32x4 acc[2][4];
    f32x4 accS[2];
    #pragma unroll
    for (int ti = 0; ti < 2; ++ti) {
        accS[ti] = (f32x4){0.f, 0.f, 0.f, 0.f};
        #pragma unroll
        for (int tf = 0; tf < 4; ++tf) acc[ti][tf] = (f32x4){0.f, 0.f, 0.f, 0.f};
    }

    for (int t = 0; t < 16; ++t) {
        int j0 = t * 32 + kg * 8;
        // loads (independent; TLP + compiler pipelining hide L2 latency)
        float4 sv0 = *(const float4*)(sd + j0);
        float4 sv1 = *(const float4*)(sd + j0 + 4);
        float4 m00 = *(const float4*)(mb0 + j0);
        float4 m01 = *(const float4*)(mb0 + j0 + 4);
        float4 m10 = *(const float4*)(mb1 + j0);
        float4 m11 = *(const float4*)(mb1 + j0 + 4);
        bf16x8 Bv0 = *(const bf16x8*)(Bbase + (size_t)0 * 16 * NN + j0);
        bf16x8 Bv1 = *(const bf16x8*)(Bbase + (size_t)1 * 16 * NN + j0);
        bf16x8 Bv2 = *(const bf16x8*)(Bbase + (size_t)2 * 16 * NN + j0);
        bf16x8 Bv3 = *(const bf16x8*)(Bbase + (size_t)3 * 16 * NN + j0);

        // e-compute == A-fragments, fully in-lane
        u16x8 a0, a1;
        {
            float x;
            x = s0 + sv0.x; x = x > 0.f ? x : NEG_SLOPE * x; a0[0] = f2bf(__expf(x + m00.x));
            x = s0 + sv0.y; x = x > 0.f ? x : NEG_SLOPE * x; a0[1] = f2bf(__expf(x + m00.y));
            x = s0 + sv0.z; x = x > 0.f ? x : NEG_SLOPE * x; a0[2] = f2bf(__expf(x + m00.z));
            x = s0 + sv0.w; x = x > 0.f ? x : NEG_SLOPE * x; a0[3] = f2bf(__expf(x + m00.w));
            x = s0 + sv1.x; x = x > 0.f ? x : NEG_SLOPE * x; a0[4] = f2bf(__expf(x + m01.x));
            x = s0 + sv1.y; x = x > 0.f ? x : NEG_SLOPE * x; a0[5] = f2bf(__expf(x + m01.y));
            x = s0 + sv1.z; x = x > 0.f ? x : NEG_SLOPE * x; a0[6] = f2bf(__expf(x + m01.z));
            x = s0 + sv1.w; x = x > 0.f ? x : NEG_SLOPE * x; a0[7] = f2bf(__expf(x + m01.w));
            x = s1 + sv0.x; x = x > 0.f ? x : NEG_SLOPE * x; a1[0] = f2bf(__expf(x + m10.x));
            x = s1 + sv0.y; x = x > 0.f ? x : NEG_SLOPE * x; a1[1] = f2bf(__expf(x + m10.y));
            x = s1 + sv0.z; x = x > 0.f ? x : NEG_SLOPE * x; a1[2] = f2bf(__expf(x + m10.z));
            x = s1 + sv0.w; x = x > 0.f ? x : NEG_SLOPE * x; a1[3] = f2bf(__expf(x + m10.w));
            x = s1 + sv1.x; x = x > 0.f ? x : NEG_SLOPE * x; a1[4] = f2bf(__expf(x + m11.x));
            x = s1 + sv1.y; x = x > 0.f ? x : NEG_SLOPE * x; a1[5] = f2bf(__expf(x + m11.y));
            x = s1 + sv1.z; x = x > 0.f ? x : NEG_SLOPE * x; a1[6] = f2bf(__expf(x + m11.z));
            x = s1 + sv1.w; x = x > 0.f ? x : NEG_SLOPE * x; a1[7] = f2bf(__expf(x + m11.w));
        }
        bf16x8 A0 = __builtin_bit_cast(bf16x8, a0);
        bf16x8 A1 = __builtin_bit_cast(bf16x8, a1);

        __builtin_amdgcn_s_setprio(1);
        acc[0][0] = __builtin_amdgcn_mfma_f32_16x16x32_bf16(A0, Bv0, acc[0][0], 0, 0, 0);
        acc[0][1] = __builtin_amdgcn_mfma_f32_16x16x32_bf16(A0, Bv1, acc[0][1], 0, 0, 0);
        acc[0][2] = __builtin_amdgcn_mfma_f32_16x16x32_bf16(A0, Bv2, acc[0][2], 0, 0, 0);
        acc[0][3] = __builtin_amdgcn_mfma_f32_16x16x32_bf16(A0, Bv3, acc[0][3], 0, 0, 0);
        accS[0]   = __builtin_amdgcn_mfma_f32_16x16x32_bf16(A0, vone, accS[0], 0, 0, 0);
        acc[1][0] = __builtin_amdgcn_mfma_f32_16x16x32_bf16(A1, Bv0, acc[1][0], 0, 0, 0);
        acc[1][1] = __builtin_amdgcn_mfma_f32_16x16x32_bf16(A1, Bv1, acc[1][1], 0, 0, 0);
        acc[1][2] = __builtin_amdgcn_mfma_f32_16x16x32_bf16(A1, Bv2, acc[1][2], 0, 0, 0);
        acc[1][3] = __builtin_amdgcn_mfma_f32_16x16x32_bf16(A1, Bv3, acc[1][3], 0, 0, 0);
        accS[1]   = __builtin_amdgcn_mfma_f32_16x16x32_bf16(A1, vone, accS[1], 0, 0, 0);
        __builtin_amdgcn_s_setprio(0);
    }

    // normalize + write this head's tile into LDS
    #pragma unroll
    for (int ti = 0; ti < 2; ++ti)
        #pragma unroll
        for (int tf = 0; tf < 4; ++tf)
            #pragma unroll
            for (int r = 0; r < 4; ++r)
                red[h][ti * 16 + kg * 4 + r][tf * 16 + col] = acc[ti][tf][r] / accS[ti][r];
    __syncthreads();

    // head-mean reduce: thread -> (i = tid>>4, 4 f at (tid&15)*4)
    int i = tid >> 4;
    int fq = (tid & 15) * 4;
    float4 s = {0.f, 0.f, 0.f, 0.f};
    #pragma unroll
    for (int w = 0; w < NH; ++w) {
        float4 v = *(const float4*)&red[w][i][fq];
        s.x += v.x; s.y += v.y; s.z += v.z; s.w += v.w;
    }
    s.x *= 0.125f; s.y *= 0.125f; s.z *= 0.125f; s.w *= 0.125f;
    *(float4*)&out[((size_t)(b * NN) + i0 + i) * NF + f0 + fq] = s;
}

extern "C" void kernel_launch(void* const* d_in, const int* in_sizes, int n_in,
                              void* d_out, int out_size, void* d_ws, size_t ws_size,
                              hipStream_t stream)
{
    const float* h    = (const float*)d_in[0];
    const int*   adj  = (const int*)d_in[1];
    const float* bias = (const float*)d_in[2];
    const float* W    = (const float*)d_in[3];
    const float* a    = (const float*)d_in[4];
    float* out = (float*)d_out;

    char* ws = (char*)d_ws;
    unsigned short* hpT  = (unsigned short*)ws;   ws += (size_t)NB * NH * NF * NN * 2;   // 16.78 MB
    float* mb    = (float*)ws;                    ws += (size_t)NN * NN * 4;             // 1 MB
    float* ssrc  = (float*)ws;                    ws += (size_t)NB * NN * NH * 4;
    float* sdstT = (float*)ws;                    ws += (size_t)NB * NN * NH * 4;
    float* wasrc = (float*)ws;                    ws += NH * NF * 4;
    float* wadst = (float*)ws;                    ws += NH * NF * 4;
    unsigned short* hHi  = (unsigned short*)ws;   ws += (size_t)NB * NN * NF * 2;        // 2 MB
    unsigned short* hLo  = (unsigned short*)ws;   ws += (size_t)NB * NN * NF * 2;
    unsigned short* wtHi = (unsigned short*)ws;   ws += (size_t)NH * NF * NF * 2;
    unsigned short* wtLo = (unsigned short*)ws;   ws += (size_t)NH * NF * NF * 2;

    hipLaunchKernelGGL(prep_all_kernel, dim3((NB * NN * NF) / 256), dim3(256), 0, stream,
                       h, adj, bias, W, a, mb, hHi, hLo, wtHi, wtLo, wasrc, wadst);
    hipLaunchKernelGGL(score_kernel, dim3((NB * NN * NH) / 256), dim3(256), 0, stream,
                       h, wasrc, wadst, ssrc, sdstT);
    hipLaunchKernelGGL(hprime_kernel, dim3(64 * 16), dim3(256), 0, stream,
                       hHi, hLo, wtHi, wtLo, hpT);
    hipLaunchKernelGGL(attn_kernel, dim3(NB * 32), dim3(512), 0, stream,
                       hpT, mb, ssrc, sdstT, out);
}

// Round 7
// 161.211 us; speedup vs baseline: 1.1279x; 1.1279x over previous
//
#include <hip/hip_runtime.h>
#include <hip/hip_bf16.h>

#define NB 16
#define NN 512
#define NH 8
#define NF 128
#define NEG_SLOPE 0.2f

typedef short bf16x8 __attribute__((ext_vector_type(8)));
typedef unsigned short u16x8 __attribute__((ext_vector_type(8)));
typedef float f32x4 __attribute__((ext_vector_type(4)));

__device__ inline unsigned short f2bf(float x) {
    __hip_bfloat16 b = __float2bfloat16(x);          // RNE hardware convert
    return __builtin_bit_cast(unsigned short, b);
}
__device__ inline float bf2f(unsigned short u) {
    return __uint_as_float(((unsigned int)u) << 16);
}

// ---------------- fused prep: emb=exp(mb) bf16, h hi/lo split, W^T hi/lo split, wa ----------------
__global__ __launch_bounds__(256) void prep_all_kernel(
    const float* __restrict__ h, const int* __restrict__ adj,
    const float* __restrict__ bias, const float* __restrict__ W,
    const float* __restrict__ a,
    unsigned short* __restrict__ emb,
    unsigned short* __restrict__ hHi, unsigned short* __restrict__ hLo,
    unsigned short* __restrict__ wtHi, unsigned short* __restrict__ wtLo,
    float* __restrict__ wasrc, float* __restrict__ wadst)
{
    int t = blockIdx.x * 256 + threadIdx.x;      // grid covers NB*NN*NF = 1048576
    {
        float v = h[t];
        unsigned short hi = f2bf(v);
        hHi[t] = hi;
        hLo[t] = f2bf(v - bf2f(hi));
    }
    if (t < NN * NN) emb[t] = (adj[t] != 0) ? f2bf(__expf(bias[t])) : (unsigned short)0;
    if (t < NH * NF * NF) {
        // coalesced READ of W in natural order; scattered 2B writes (fire-and-forget)
        float v = W[t];                          // t = (hh*128 + k)*128 + f
        int hh = t >> 14;
        int k  = (t >> 7) & 127;
        int f  = t & 127;
        int u  = (hh * NF + f) * NF + k;         // wt[f_global][k]
        unsigned short hi = f2bf(v);
        wtHi[u] = hi;
        wtLo[u] = f2bf(v - bf2f(hi));
    }
    if (t < NH * NF) {
        int hh = t >> 7, i = t & 127;
        const float4* wrow = (const float4*)(W + (hh * NF + i) * NF);
        const float4* asr = (const float4*)(a + hh * 2 * NF);
        const float4* ads = (const float4*)(a + hh * 2 * NF + NF);
        float s1 = 0.f, s2 = 0.f;
        #pragma unroll 8
        for (int f = 0; f < NF / 4; ++f) {
            float4 w = wrow[f], x = asr[f], y = ads[f];
            s1 += w.x * x.x + w.y * x.y + w.z * x.z + w.w * x.w;
            s2 += w.x * y.x + w.y * y.y + w.z * y.z + w.w * y.w;
        }
        wasrc[t] = s1; wadst[t] = s2;
    }
}

// ---------------- scores: f32-exact; sdst stored transposed [b][h][n] ----------------
__global__ __launch_bounds__(256) void score_kernel(
    const float* __restrict__ h, const float* __restrict__ wasrc,
    const float* __restrict__ wadst, float* __restrict__ ssrc, float* __restrict__ sdstT)
{
    __shared__ float wsm[2][NH * (NF + 4)];
    int tid = threadIdx.x;
    for (int u = tid; u < NH * NF; u += 256) {
        int hh = u >> 7, f = u & 127;
        wsm[0][hh * (NF + 4) + f] = wasrc[u];
        wsm[1][hh * (NF + 4) + f] = wadst[u];
    }
    __syncthreads();
    int t = blockIdx.x * 256 + tid;           // over B*N*H
    int hh = t & 7;
    int bn = t >> 3;
    int b = bn >> 9, n = bn & 511;
    const float4* hrow = (const float4*)(h + (size_t)bn * NF);
    const float4* w1 = (const float4*)(&wsm[0][hh * (NF + 4)]);
    const float4* w2 = (const float4*)(&wsm[1][hh * (NF + 4)]);
    float s1 = 0.f, s2 = 0.f;
    #pragma unroll
    for (int u = 0; u < NF / 4; ++u) {
        float4 hv = hrow[u], a1 = w1[u], a2 = w2[u];
        s1 += hv.x * a1.x + hv.y * a1.y + hv.z * a1.z + hv.w * a1.w;
        s2 += hv.x * a2.x + hv.y * a2.y + hv.z * a2.z + hv.w * a2.w;
    }
    ssrc[t] = s1;
    sdstT[((size_t)(b * NH + hh)) * NN + n] = s2;
}

// ---------------- h_prime v2: wt-in-registers, streamed n-tiles -> hpT[b][hf][n] ----------------
__global__ __launch_bounds__(256, 4) void hprime_kernel(
    const unsigned short* __restrict__ hHi, const unsigned short* __restrict__ hLo,
    const unsigned short* __restrict__ wtHi, const unsigned short* __restrict__ wtLo,
    unsigned short* __restrict__ hpT)
{
    int bx = blockIdx.x;
    int nchunk = bx & 63;                      // 64 chunks of 128 n-rows
    int hfg = bx >> 6;                         // 0..15
    int hh = hfg >> 1, fg = hfg & 1;
    int tid = threadIdx.x;
    int wave = tid >> 6, lane = tid & 63;
    int col = lane & 15, kg = lane >> 4;
    int fbase = hh * NF + fg * 64 + wave * 16;
    int n0g = nchunk * 128;
    int b = n0g >> 9;
    int nin = n0g & 511;

    const unsigned short* Bh = wtHi + (size_t)(fbase + col) * NF + kg * 8;
    const unsigned short* Bl = wtLo + (size_t)(fbase + col) * NF + kg * 8;
    bf16x8 bh[4], bl[4];
    #pragma unroll
    for (int ks = 0; ks < 4; ++ks) {
        bh[ks] = *(const bf16x8*)(Bh + ks * 32);
        bl[ks] = *(const bf16x8*)(Bl + ks * 32);
    }

    size_t outRow = ((size_t)b * (NH * NF) + fbase + col) * NN;

    #pragma unroll 2
    for (int nt = 0; nt < 8; ++nt) {
        const unsigned short* Ah = hHi + (size_t)(n0g + nt * 16 + col) * NF + kg * 8;
        const unsigned short* Al = hLo + (size_t)(n0g + nt * 16 + col) * NF + kg * 8;
        bf16x8 ah[4], al[4];
        #pragma unroll
        for (int ks = 0; ks < 4; ++ks) {
            ah[ks] = *(const bf16x8*)(Ah + ks * 32);
            al[ks] = *(const bf16x8*)(Al + ks * 32);
        }
        f32x4 acc = {0.f, 0.f, 0.f, 0.f};
        #pragma unroll
        for (int ks = 0; ks < 4; ++ks) {
            acc = __builtin_amdgcn_mfma_f32_16x16x32_bf16(ah[ks], bh[ks], acc, 0, 0, 0);
            acc = __builtin_amdgcn_mfma_f32_16x16x32_bf16(al[ks], bh[ks], acc, 0, 0, 0);
            acc = __builtin_amdgcn_mfma_f32_16x16x32_bf16(ah[ks], bl[ks], acc, 0, 0, 0);
        }
        ushort4 u;
        u.x = f2bf(acc[0]); u.y = f2bf(acc[1]);
        u.z = f2bf(acc[2]); u.w = f2bf(acc[3]);
        *(ushort4*)&hpT[outRow + nin + nt * 16 + kg * 4] = u;
    }
}

// ---------------- A-fragment compute: 8 e-values -> bf16, fully in-lane ----------------
__device__ inline bf16x8 make_afrag(float s, float4 v0, float4 v1, bf16x8 eb) {
    u16x8 ebu = __builtin_bit_cast(u16x8, eb);
    u16x8 r;
    float x;
    x = s + v0.x; x = fmaxf(x, NEG_SLOPE * x); r[0] = f2bf(__expf(x) * bf2f(ebu[0]));
    x = s + v0.y; x = fmaxf(x, NEG_SLOPE * x); r[1] = f2bf(__expf(x) * bf2f(ebu[1]));
    x = s + v0.z; x = fmaxf(x, NEG_SLOPE * x); r[2] = f2bf(__expf(x) * bf2f(ebu[2]));
    x = s + v0.w; x = fmaxf(x, NEG_SLOPE * x); r[3] = f2bf(__expf(x) * bf2f(ebu[3]));
    x = s + v1.x; x = fmaxf(x, NEG_SLOPE * x); r[4] = f2bf(__expf(x) * bf2f(ebu[4]));
    x = s + v1.y; x = fmaxf(x, NEG_SLOPE * x); r[5] = f2bf(__expf(x) * bf2f(ebu[5]));
    x = s + v1.z; x = fmaxf(x, NEG_SLOPE * x); r[6] = f2bf(__expf(x) * bf2f(ebu[6]));
    x = s + v1.w; x = fmaxf(x, NEG_SLOPE * x); r[7] = f2bf(__expf(x) * bf2f(ebu[7]));
    return __builtin_bit_cast(bf16x8, r);
}

// ---------------- attention v4: full-f wave, depth-2 pipelined, e-computed once ----------------
// grid 256: bx = ipair*16 + b  (same-b blocks share XCD). 512 threads = 8 waves = 8 heads.
// Wave owns C[32 i][128 f] for its head. Zero barriers in j-loop; 3 for head-mean.
__global__ __launch_bounds__(512, 2) void attn_kernel(
    const unsigned short* __restrict__ hpT, const unsigned short* __restrict__ emb,
    const float* __restrict__ ssrc, const float* __restrict__ sdstT,
    float* __restrict__ out)
{
    __shared__ float red[NH][16][NF + 4];      // 67.6 KB, pad -> conflict-light
    int bx = blockIdx.x;
    int b = bx & 15;
    int ipair = bx >> 4;                       // 0..15
    int i0 = ipair * 32;
    int tid = threadIdx.x;
    int lane = tid & 63, h = tid >> 6;
    int col = lane & 15, kg = lane >> 4;

    const short one_bf = (short)0x3f80;
    const bf16x8 vone = {one_bf, one_bf, one_bf, one_bf, one_bf, one_bf, one_bf, one_bf};

    const float* sd = sdstT + (size_t)(b * NH + h) * NN;
    float s0 = ssrc[((size_t)(b * NN) + i0 + col) * NH + h];
    float s1 = ssrc[((size_t)(b * NN) + i0 + 16 + col) * NH + h];
    const unsigned short* eb0p = emb + (size_t)(i0 + col) * NN;
    const unsigned short* eb1p = emb + (size_t)(i0 + 16 + col) * NN;
    const unsigned short* Bbase = hpT + ((size_t)(b * NH + h) * NF + col) * NN;

    f32x4 acc[2][8];
    f32x4 accS[2];
    #pragma unroll
    for (int ti = 0; ti < 2; ++ti) {
        accS[ti] = (f32x4){0.f, 0.f, 0.f, 0.f};
        #pragma unroll
        for (int tf = 0; tf < 8; ++tf) acc[ti][tf] = (f32x4){0.f, 0.f, 0.f, 0.f};
    }

    // depth-2 ping-pong for sd/emb (statically indexed after full unroll)
    float4 sv0[2], sv1[2];
    bf16x8 eb0v[2], eb1v[2];
    {
        int j = kg * 8;
        sv0[0] = *(const float4*)(sd + j);
        sv1[0] = *(const float4*)(sd + j + 4);
        eb0v[0] = *(const bf16x8*)(eb0p + j);
        eb1v[0] = *(const bf16x8*)(eb1p + j);
    }

    #pragma unroll
    for (int t = 0; t < 16; ++t) {
        const int cur = t & 1, nxt = cur ^ 1;
        const int jc = t * 32 + kg * 8;
        // issue next-iteration sd/emb loads (consumed next body -> full body of cover)
        if (t < 15) {
            const int jn = jc + 32;
            sv0[nxt] = *(const float4*)(sd + jn);
            sv1[nxt] = *(const float4*)(sd + jn + 4);
            eb0v[nxt] = *(const bf16x8*)(eb0p + jn);
            eb1v[nxt] = *(const bf16x8*)(eb1p + jn);
        }
        // issue current B loads; their L2 latency hides under the A-frag VALU block
        bf16x8 Bv[8];
        #pragma unroll
        for (int tf = 0; tf < 8; ++tf)
            Bv[tf] = *(const bf16x8*)(Bbase + (size_t)tf * 16 * NN + jc);

        bf16x8 A0 = make_afrag(s0, sv0[cur], sv1[cur], eb0v[cur]);
        bf16x8 A1 = make_afrag(s1, sv0[cur], sv1[cur], eb1v[cur]);

        __builtin_amdgcn_s_setprio(1);
        #pragma unroll
        for (int tf = 0; tf < 8; ++tf) {
            acc[0][tf] = __builtin_amdgcn_mfma_f32_16x16x32_bf16(A0, Bv[tf], acc[0][tf], 0, 0, 0);
            acc[1][tf] = __builtin_amdgcn_mfma_f32_16x16x32_bf16(A1, Bv[tf], acc[1][tf], 0, 0, 0);
        }
        accS[0] = __builtin_amdgcn_mfma_f32_16x16x32_bf16(A0, vone, accS[0], 0, 0, 0);
        accS[1] = __builtin_amdgcn_mfma_f32_16x16x32_bf16(A1, vone, accS[1], 0, 0, 0);
        __builtin_amdgcn_s_setprio(0);
    }

    // ---- head-mean: 2 rounds through 64KB LDS ----
    int fr = tid & 127;                        // reduce: lanes -> consecutive f
    int iq = tid >> 7;                         // 0..3
    #pragma unroll
    for (int ti = 0; ti < 2; ++ti) {
        #pragma unroll
        for (int tf = 0; tf < 8; ++tf)
            #pragma unroll
            for (int r = 0; r < 4; ++r)
                red[h][kg * 4 + r][tf * 16 + col] = acc[ti][tf][r] / accS[ti][r];
        __syncthreads();
        #pragma unroll
        for (int q = 0; q < 4; ++q) {
            int i = iq * 4 + q;
            float sacc = 0.f;
            #pragma unroll
            for (int w = 0; w < NH; ++w) sacc += red[w][i][fr];
            out[((size_t)(b * NN) + i0 + ti * 16 + i) * NF + fr] = sacc * 0.125f;
        }
        if (ti == 0) __syncthreads();
    }
}

extern "C" void kernel_launch(void* const* d_in, const int* in_sizes, int n_in,
                              void* d_out, int out_size, void* d_ws, size_t ws_size,
                              hipStream_t stream)
{
    const float* h    = (const float*)d_in[0];
    const int*   adj  = (const int*)d_in[1];
    const float* bias = (const float*)d_in[2];
    const float* W    = (const float*)d_in[3];
    const float* a    = (const float*)d_in[4];
    float* out = (float*)d_out;

    char* ws = (char*)d_ws;
    unsigned short* hpT  = (unsigned short*)ws;   ws += (size_t)NB * NH * NF * NN * 2;   // 16.78 MB
    unsigned short* emb  = (unsigned short*)ws;   ws += (size_t)NN * NN * 2;             // 0.5 MB
    float* ssrc  = (float*)ws;                    ws += (size_t)NB * NN * NH * 4;
    float* sdstT = (float*)ws;                    ws += (size_t)NB * NN * NH * 4;
    float* wasrc = (float*)ws;                    ws += NH * NF * 4;
    float* wadst = (float*)ws;                    ws += NH * NF * 4;
    unsigned short* hHi  = (unsigned short*)ws;   ws += (size_t)NB * NN * NF * 2;        // 2 MB
    unsigned short* hLo  = (unsigned short*)ws;   ws += (size_t)NB * NN * NF * 2;
    unsigned short* wtHi = (unsigned short*)ws;   ws += (size_t)NH * NF * NF * 2;
    unsigned short* wtLo = (unsigned short*)ws;   ws += (size_t)NH * NF * NF * 2;

    hipLaunchKernelGGL(prep_all_kernel, dim3((NB * NN * NF) / 256), dim3(256), 0, stream,
                       h, adj, bias, W, a, emb, hHi, hLo, wtHi, wtLo, wasrc, wadst);
    hipLaunchKernelGGL(score_kernel, dim3((NB * NN * NH) / 256), dim3(256), 0, stream,
                       h, wasrc, wadst, ssrc, sdstT);
    hipLaunchKernelGGL(hprime_kernel, dim3(64 * 16), dim3(256), 0, stream,
                       hHi, hLo, wtHi, wtLo, hpT);
    hipLaunchKernelGGL(attn_kernel, dim3(NB * 16), dim3(512), 0, stream,
                       hpT, emb, ssrc, sdstT, out);
}